// Round 8
// baseline (542.113 us; speedup 1.0000x reference)
//
#include <hip/hip_runtime.h>

typedef unsigned long long u64;

#define N1c 4096
#define N2c 49152
#define Dc 512
#define SPLITc 24576
#define NSPLITc 2
#define CAPc 65536
#define WPSc (SPLITc / 64)   /* 384 mask words per row per split */
#define SIM_Tc 0.2f
#define AMB_Tc 0.17f
#define DELTAc 0.01f         /* bf16-vs-f32 safety band half-width (bound ~0.008) */
#define CANDMAX (1 << 20)

typedef __bf16 bf16x8 __attribute__((ext_vector_type(8)));
typedef float f32x4 __attribute__((ext_vector_type(4)));

static __device__ __forceinline__ unsigned short f2bf(float x) {
  unsigned u = __float_as_uint(x);
  unsigned r = (u + 0x7fffu + ((u >> 16) & 1u)) >> 16;   // RNE
  return (unsigned short)r;
}

// ---------------------------------------------------------------- fill out=-1
__global__ void sim_fill_out_k(int* __restrict__ out, int n) {
  int i = blockIdx.x * blockDim.x + threadIdx.x;
  if (i < n) out[i] = -1;
}

__global__ void sim_zero_k(int* __restrict__ p) { if (threadIdx.x == 0) *p = 0; }

// ---------------------------------------------------------------- norms (+ bf16 queries + split-0 db)
__global__ void sim_norm_k(const float* __restrict__ f1, const float* __restrict__ f2,
                           float* __restrict__ invn, unsigned short* __restrict__ f1nb,
                           unsigned short* __restrict__ f2nb) {
  int wid = threadIdx.x >> 6, lane = threadIdx.x & 63;
  int row = blockIdx.x * 4 + wid;
  if (row >= N1c + N2c) return;
  const float* src = (row < N1c) ? (f1 + (size_t)row * Dc)
                                 : (f2 + (size_t)(row - N1c) * Dc);
  const float4* p = (const float4*)src;
  float4 v0 = p[lane];
  float4 v1 = p[lane + 64];
  float ss = v0.x*v0.x + v0.y*v0.y + v0.z*v0.z + v0.w*v0.w
           + v1.x*v1.x + v1.y*v1.y + v1.z*v1.z + v1.w*v1.w;
  #pragma unroll
  for (int d = 1; d < 64; d <<= 1) ss += __shfl_xor(ss, d);
  float inv = 1.0f / fmaxf(sqrtf(ss), 1e-12f);
  if (lane == 0) invn[row] = inv;
  unsigned short* dst = 0;
  if (row < N1c) dst = f1nb + (size_t)row * Dc;
  else if (row < N1c + SPLITc) dst = f2nb + (size_t)(row - N1c) * Dc;
  if (dst) {
    ushort4 o0, o1;
    o0.x = f2bf(v0.x*inv); o0.y = f2bf(v0.y*inv); o0.z = f2bf(v0.z*inv); o0.w = f2bf(v0.w*inv);
    o1.x = f2bf(v1.x*inv); o1.y = f2bf(v1.y*inv); o1.z = f2bf(v1.z*inv); o1.w = f2bf(v1.w*inv);
    ushort4* q = (ushort4*)dst;
    q[lane] = o0; q[lane + 64] = o1;
  }
}

// ---------------------------------------------------------------- per-split db -> normalized bf16 (split 1 only)
__global__ void sim_conv2_k(const float* __restrict__ f2, const float* __restrict__ invn,
                            unsigned short* __restrict__ f2nb, int s) {
  int wid = threadIdx.x >> 6, lane = threadIdx.x & 63;
  int rloc = blockIdx.x * 4 + wid;
  if (rloc >= SPLITc) return;
  int grow = s * SPLITc + rloc;
  float inv = invn[N1c + grow];
  const float4* p = (const float4*)(f2 + (size_t)grow * Dc);
  float4 v0 = p[lane];
  float4 v1 = p[lane + 64];
  ushort4 o0, o1;
  o0.x = f2bf(v0.x*inv); o0.y = f2bf(v0.y*inv); o0.z = f2bf(v0.z*inv); o0.w = f2bf(v0.w*inv);
  o1.x = f2bf(v1.x*inv); o1.y = f2bf(v1.y*inv); o1.z = f2bf(v1.z*inv); o1.w = f2bf(v1.w*inv);
  ushort4* q = (ushort4*)(f2nb + (size_t)rloc * Dc);
  q[lane] = o0; q[lane + 64] = o1;
}

// ---------------------------------------------------------------- bf16 MFMA GEMM + classify
// 128x128 tile (round-3 proven geometry), BK=64, 4 waves (2x2), 4x4 frags of
// 16x16x32 per wave. NEW vs round 3: double-buffered LDS (68 KiB -> 2
// blocks/CU) with stage(t+1) issued BEFORE compute(t) and ONE barrier per
// K-step. Two overlap mechanisms: loads fly during own compute AND the
// co-resident block computes during the residual drain.
__global__ __launch_bounds__(256, 2) void sim_mfma_k(
    const unsigned short* __restrict__ Abf, const unsigned short* __restrict__ Bbf,
    const int* __restrict__ labels, const int* __restrict__ indexes,
    const int* __restrict__ labels_db, const int* __restrict__ indexes_db,
    u64* __restrict__ msim, u64* __restrict__ mamb,
    unsigned* __restrict__ cands, int* __restrict__ ccount, int s)
{
  __shared__ __align__(16) unsigned short As[2][128 * 64];   // 2 x 16 KB
  __shared__ __align__(16) unsigned short Bs[2][128 * 64];   // 2 x 16 KB
  __shared__ u64 wS[128][2];                                 // 2 KB
  __shared__ u64 wA[128][2];                                 // 2 KB

  const int tid  = threadIdx.x;
  const int lane = tid & 63;
  const int wid  = tid >> 6;
  const int wm   = wid >> 1, wn = wid & 1;
  const int rbase = blockIdx.y * 128;
  const int cbase = blockIdx.x * 128;      // column within split

  // zero mask staging (before first barrier; only touched again after K-loop)
  wS[tid >> 1][tid & 1] = 0;
  wA[tid >> 1][tid & 1] = 0;

  f32x4 acc[4][4];
  #pragma unroll
  for (int i = 0; i < 4; ++i)
    #pragma unroll
    for (int j = 0; j < 4; ++j) acc[i][j] = (f32x4){0.f, 0.f, 0.f, 0.f};

  // stage one BK=64 K-tile of A and B into buffer pb (8 loads/thread)
  // layout/swizzle verbatim from round 3 (bank-conflict-free, measured)
#define STAGE_T(pb, kb) do {                                                     \
    _Pragma("unroll")                                                            \
    for (int c4_ = 0; c4_ < 4; ++c4_) {                                          \
      int c_   = wid * 4 + c4_;               /* chunk 0..15 (8 rows each) */    \
      int row_ = c_ * 8 + (lane >> 3);                                           \
      int ls_  = (lane & 7) ^ (row_ & 7);     /* logical k-slot for phys slot */ \
      const unsigned short* ga_ = Abf + (size_t)(rbase + row_) * Dc + (kb) + ls_ * 8; \
      const unsigned short* gb_ = Bbf + (size_t)(cbase + row_) * Dc + (kb) + ls_ * 8; \
      __builtin_amdgcn_global_load_lds(                                          \
          (const __attribute__((address_space(1))) void*)ga_,                    \
          (__attribute__((address_space(3))) void*)(&As[pb][c_ * 512]), 16, 0, 0); \
      __builtin_amdgcn_global_load_lds(                                          \
          (const __attribute__((address_space(1))) void*)gb_,                    \
          (__attribute__((address_space(3))) void*)(&Bs[pb][c_ * 512]), 16, 0, 0); \
    } } while (0)

#define COMPUTE_T(pb) do {                                                       \
    _Pragma("unroll")                                                            \
    for (int kk_ = 0; kk_ < 2; ++kk_) {                                          \
      bf16x8 a_[4], b_[4];                                                       \
      _Pragma("unroll")                                                          \
      for (int mi_ = 0; mi_ < 4; ++mi_) {                                        \
        int r_  = wm * 64 + mi_ * 16 + (lane & 15);                              \
        int ps_ = (kk_ * 4 + (lane >> 4)) ^ (r_ & 7);                            \
        a_[mi_] = *(const bf16x8*)(const void*)(&As[pb][r_ * 64 + ps_ * 8]);     \
      }                                                                          \
      _Pragma("unroll")                                                          \
      for (int ni_ = 0; ni_ < 4; ++ni_) {                                        \
        int r_  = wn * 64 + ni_ * 16 + (lane & 15);                              \
        int ps_ = (kk_ * 4 + (lane >> 4)) ^ (r_ & 7);                            \
        b_[ni_] = *(const bf16x8*)(const void*)(&Bs[pb][r_ * 64 + ps_ * 8]);     \
      }                                                                          \
      _Pragma("unroll")                                                          \
      for (int mi_ = 0; mi_ < 4; ++mi_)                                          \
        _Pragma("unroll")                                                        \
        for (int ni_ = 0; ni_ < 4; ++ni_)                                        \
          acc[mi_][ni_] = __builtin_amdgcn_mfma_f32_16x16x32_bf16(               \
              a_[mi_], b_[ni_], acc[mi_][ni_], 0, 0, 0);                         \
    } } while (0)

  STAGE_T(0, 0);
  __syncthreads();                     // drain prologue stage
  #pragma unroll
  for (int t = 0; t < 8; ++t) {
    if (t < 7) STAGE_T((t + 1) & 1, (t + 1) * 64);   // issue next tile EARLY
    COMPUTE_T(t & 1);                                 // ds_read + MFMA current
    __syncthreads();                  // drains vmcnt+lgkmcnt; swap safe
  }

  // ---- classify into bit masks (C layout: col=lane&15, row=(lane>>4)*4+reg) ----
  int lab2[4], idx2[4], cloc[4];
  #pragma unroll
  for (int ni = 0; ni < 4; ++ni) {
    cloc[ni] = cbase + wn * 64 + ni * 16 + (lane & 15);
    int gc = s * SPLITc + cloc[ni];
    lab2[ni] = labels_db[gc];
    idx2[ni] = indexes_db[gc];
  }

  #pragma unroll
  for (int mi = 0; mi < 4; ++mi) {
    #pragma unroll
    for (int r = 0; r < 4; ++r) {
      int row128 = wm * 64 + mi * 16 + (lane >> 4) * 4 + r;
      int gr = rbase + row128;
      int lab1 = labels[gr], idx1 = indexes[gr];
      u64 sb = 0, ab = 0;
      #pragma unroll
      for (int ni = 0; ni < 4; ++ni) {
        float v = acc[mi][ni][r];
        if (idx1 < idx2[ni] && lab1 != lab2[ni]) {
          if (v > SIM_Tc + DELTAc) {
            sb |= 1ull << (ni * 16 + (lane & 15));
          } else if (v > AMB_Tc - DELTAc) {
            if (v < SIM_Tc - DELTAc && v > AMB_Tc + DELTAc) {
              ab |= 1ull << (ni * 16 + (lane & 15));
            } else {   // within ±DELTA of a threshold: exact f32 recheck later
              int ci = atomicAdd(ccount, 1);
              if (ci < CANDMAX)
                cands[ci] = ((unsigned)gr << 15) | (unsigned)cloc[ni];
            }
          }
        }
      }
      if (sb) atomicOr(&wS[row128][wn], sb);
      if (ab) atomicOr(&wA[row128][wn], ab);
    }
  }
  __syncthreads();
  {
    int row128 = tid >> 1, jh = tid & 1;
    size_t w = (size_t)(rbase + row128) * WPSc + (cbase >> 6) + jh;
    msim[w] = wS[row128][jh];
    mamb[w] = wA[row128][jh];
  }
#undef STAGE_T
#undef COMPUTE_T
}

// ---------------------------------------------------------------- exact f32 recheck of band pairs
__global__ void sim_recheck_k(const float* __restrict__ f1, const float* __restrict__ f2,
                              const float* __restrict__ invn,
                              const unsigned* __restrict__ cands, const int* __restrict__ ccount,
                              u64* __restrict__ msim, u64* __restrict__ mamb, int s) {
  int lane = threadIdx.x & 63;
  int gw = (blockIdx.x * blockDim.x + threadIdx.x) >> 6;
  int nw = (gridDim.x * blockDim.x) >> 6;
  int n = *ccount; if (n > CANDMAX) n = CANDMAX;
  for (int i = gw; i < n; i += nw) {
    unsigned pk = cands[i];
    int r = (int)(pk >> 15), c = (int)(pk & 0x7fffu);
    const float4* pa = (const float4*)(f1 + (size_t)r * Dc);
    const float4* pb = (const float4*)(f2 + ((size_t)s * SPLITc + c) * Dc);
    float4 a0 = pa[lane], a1 = pa[lane + 64];
    float4 b0 = pb[lane], b1 = pb[lane + 64];
    float d = a0.x*b0.x + a0.y*b0.y + a0.z*b0.z + a0.w*b0.w
            + a1.x*b1.x + a1.y*b1.y + a1.z*b1.z + a1.w*b1.w;
    #pragma unroll
    for (int t = 1; t < 64; t <<= 1) d += __shfl_xor(d, t);
    if (lane == 0) {
      float v = d * invn[r] * invn[N1c + s * SPLITc + c];
      if (v > SIM_Tc)
        atomicOr(&msim[(size_t)r * WPSc + (c >> 6)], 1ull << (c & 63));
      else if (v > AMB_Tc)
        atomicOr(&mamb[(size_t)r * WPSc + (c >> 6)], 1ull << (c & 63));
    }
  }
}

// ---------------------------------------------------------------- per-row counts
__global__ void sim_rowcount_k(const u64* __restrict__ msim, const u64* __restrict__ mamb,
                               int* __restrict__ rowcnt) {
  int row = blockIdx.x;
  int wid = threadIdx.x >> 6, lane = threadIdx.x & 63;
  const u64* m = wid ? mamb : msim;
  int ssum = 0;
  #pragma unroll
  for (int it = 0; it < WPSc / 64; ++it)
    ssum += __popcll(m[(size_t)row * WPSc + it * 64 + lane]);
  #pragma unroll
  for (int d = 32; d; d >>= 1) ssum += __shfl_down(ssum, d);
  if (lane == 0) rowcnt[wid * N1c + row] = ssum;
}

// ---------------------------------------------------------------- exclusive scan over 4096 rows
__global__ void sim_scan_k(const int* __restrict__ rowcnt, int* __restrict__ rowoff) {
  int cat = blockIdx.x;
  int tid = threadIdx.x;                  // 256 threads x 16 rows
  int v[16]; int ssum = 0;
  #pragma unroll
  for (int i = 0; i < 16; ++i) { v[i] = rowcnt[cat * N1c + tid * 16 + i]; ssum += v[i]; }
  int lane = tid & 63, wid = tid >> 6;
  int incl = ssum;
  #pragma unroll
  for (int d = 1; d < 64; d <<= 1) { int t = __shfl_up(incl, d); if (lane >= d) incl += t; }
  __shared__ int wsum[4];
  if (lane == 63) wsum[wid] = incl;
  __syncthreads();
  int woff = 0;
  for (int w = 0; w < wid; ++w) woff += wsum[w];
  int run = woff + incl - ssum;
  #pragma unroll
  for (int i = 0; i < 16; ++i) { rowoff[cat * N1c + tid * 16 + i] = run; run += v[i]; }
}

// ---------------------------------------------------------------- ordered scatter
__global__ void sim_scatter_k(const u64* __restrict__ msim, const u64* __restrict__ mamb,
                              const int* __restrict__ rowoff,
                              const int* __restrict__ labels, const int* __restrict__ counts,
                              const int* __restrict__ labels_db, const int* __restrict__ counts_db,
                              int* __restrict__ out, int s) {
  int row = blockIdx.x;
  int cat = blockIdx.y;
  int lane = threadIdx.x;
  const u64* m = cat ? mamb : msim;
  int* o = out + (cat ? (NSPLITc * CAPc * 2 + s * CAPc * 2) : (s * CAPc * 2));
  int run = rowoff[cat * N1c + row];
  int lab1 = labels[row];
  int cnt1 = counts[row];
  for (int it = 0; it < WPSc / 64; ++it) {
    int w = it * 64 + lane;
    u64 x = m[(size_t)row * WPSc + w];
    int pc = __popcll(x);
    int incl = pc;
    #pragma unroll
    for (int d = 1; d < 64; d <<= 1) { int t = __shfl_up(incl, d); if (lane >= d) incl += t; }
    int pos = run + incl - pc;
    int tot = __shfl(incl, 63);
    while (x) {
      int b = __builtin_ctzll(x);
      x &= x - 1;
      if (pos < CAPc) {
        int gc = s * SPLITc + w * 64 + b;
        int l2v = labels_db[gc];
        if (cat == 0) {
          o[2 * pos]     = lab1;
          o[2 * pos + 1] = l2v;
        } else {
          bool sw = cnt1 > counts_db[gc];
          o[2 * pos]     = sw ? l2v : lab1;
          o[2 * pos + 1] = sw ? lab1 : l2v;
        }
      }
      ++pos;
    }
    run += tot;
  }
}

// ---------------------------------------------------------------- launcher
extern "C" void kernel_launch(void* const* d_in, const int* in_sizes, int n_in,
                              void* d_out, int out_size, void* d_ws, size_t ws_size,
                              hipStream_t stream) {
  const float* features    = (const float*)d_in[0];
  const int*   labels      = (const int*)  d_in[1];
  const int*   counts      = (const int*)  d_in[2];
  const int*   indexes     = (const int*)  d_in[3];
  const float* features_db = (const float*)d_in[4];
  const int*   labels_db   = (const int*)  d_in[5];
  const int*   counts_db   = (const int*)  d_in[6];
  const int*   indexes_db  = (const int*)  d_in[7];
  int* out = (int*)d_out;

  // workspace layout (~57.5 MB)
  u64*   msim   = (u64*)d_ws;                           // 12.58 MB
  u64*   mamb   = msim + (size_t)N1c * WPSc;            // 12.58 MB
  float* invn   = (float*)(mamb + (size_t)N1c * WPSc);  // (N1+N2) f32
  int*   rowcnt = (int*)(invn + (N1c + N2c));           // [2][N1]
  int*   rowoff = rowcnt + 2 * N1c;                     // [2][N1]
  int*   ccount = rowoff + 2 * N1c;                     // 1 (+pad)
  unsigned* cands = (unsigned*)(ccount + 4);            // 4 MB
  unsigned short* f1nb = (unsigned short*)(cands + CANDMAX);  // 4 MB
  unsigned short* f2nb = f1nb + (size_t)N1c * Dc;       // 24 MB (per split, reused)

  sim_fill_out_k<<<(out_size + 255) / 256, 256, 0, stream>>>(out, out_size);
  sim_norm_k<<<(N1c + N2c + 3) / 4, 256, 0, stream>>>(features, features_db, invn, f1nb, f2nb);

  for (int s = 0; s < NSPLITc; ++s) {
    if (s) sim_conv2_k<<<SPLITc / 4, 256, 0, stream>>>(features_db, invn, f2nb, s);
    sim_zero_k<<<1, 64, 0, stream>>>(ccount);
    sim_mfma_k<<<dim3(SPLITc / 128, N1c / 128), 256, 0, stream>>>(
        f1nb, f2nb, labels, indexes, labels_db, indexes_db,
        msim, mamb, cands, ccount, s);
    sim_recheck_k<<<512, 256, 0, stream>>>(features, features_db, invn,
                                           cands, ccount, msim, mamb, s);
    sim_rowcount_k<<<N1c, 128, 0, stream>>>(msim, mamb, rowcnt);
    sim_scan_k<<<2, 256, 0, stream>>>(rowcnt, rowoff);
    sim_scatter_k<<<dim3(N1c, 2), 64, 0, stream>>>(
        msim, mamb, rowoff, labels, counts, labels_db, counts_db, out, s);
  }
}

// Round 9
// 372.085 us; speedup vs baseline: 1.4570x; 1.4570x over previous
//
#include <hip/hip_runtime.h>

typedef unsigned long long u64;

#define N1c 4096
#define N2c 49152
#define Dc 512
#define SPLITc 24576
#define NSPLITc 2
#define CAPc 65536
#define WPSc (SPLITc / 64)   /* 384 mask words per row per split */
#define SIM_Tc 0.2f
#define AMB_Tc 0.17f
#define DELTAc 0.01f         /* bf16-vs-f32 safety band half-width (bound ~0.008) */
#define CANDMAX (1 << 20)

typedef __bf16 bf16x8 __attribute__((ext_vector_type(8)));
typedef float f32x4 __attribute__((ext_vector_type(4)));

static __device__ __forceinline__ unsigned short f2bf(float x) {
  unsigned u = __float_as_uint(x);
  unsigned r = (u + 0x7fffu + ((u >> 16) & 1u)) >> 16;   // RNE
  return (unsigned short)r;
}

// ---------------------------------------------------------------- fill out=-1
__global__ void sim_fill_out_k(int* __restrict__ out, int n) {
  int i = blockIdx.x * blockDim.x + threadIdx.x;
  if (i < n) out[i] = -1;
}

__global__ void sim_zero_k(int* __restrict__ p) { if (threadIdx.x == 0) *p = 0; }

// ---------------------------------------------------------------- norms (+ bf16 queries + split-0 db)
__global__ void sim_norm_k(const float* __restrict__ f1, const float* __restrict__ f2,
                           float* __restrict__ invn, unsigned short* __restrict__ f1nb,
                           unsigned short* __restrict__ f2nb) {
  int wid = threadIdx.x >> 6, lane = threadIdx.x & 63;
  int row = blockIdx.x * 4 + wid;
  if (row >= N1c + N2c) return;
  const float* src = (row < N1c) ? (f1 + (size_t)row * Dc)
                                 : (f2 + (size_t)(row - N1c) * Dc);
  const float4* p = (const float4*)src;
  float4 v0 = p[lane];
  float4 v1 = p[lane + 64];
  float ss = v0.x*v0.x + v0.y*v0.y + v0.z*v0.z + v0.w*v0.w
           + v1.x*v1.x + v1.y*v1.y + v1.z*v1.z + v1.w*v1.w;
  #pragma unroll
  for (int d = 1; d < 64; d <<= 1) ss += __shfl_xor(ss, d);
  float inv = 1.0f / fmaxf(sqrtf(ss), 1e-12f);
  if (lane == 0) invn[row] = inv;
  unsigned short* dst = 0;
  if (row < N1c) dst = f1nb + (size_t)row * Dc;
  else if (row < N1c + SPLITc) dst = f2nb + (size_t)(row - N1c) * Dc;
  if (dst) {
    ushort4 o0, o1;
    o0.x = f2bf(v0.x*inv); o0.y = f2bf(v0.y*inv); o0.z = f2bf(v0.z*inv); o0.w = f2bf(v0.w*inv);
    o1.x = f2bf(v1.x*inv); o1.y = f2bf(v1.y*inv); o1.z = f2bf(v1.z*inv); o1.w = f2bf(v1.w*inv);
    ushort4* q = (ushort4*)dst;
    q[lane] = o0; q[lane + 64] = o1;
  }
}

// ---------------------------------------------------------------- per-split db -> normalized bf16 (split 1 only)
__global__ void sim_conv2_k(const float* __restrict__ f2, const float* __restrict__ invn,
                            unsigned short* __restrict__ f2nb, int s) {
  int wid = threadIdx.x >> 6, lane = threadIdx.x & 63;
  int rloc = blockIdx.x * 4 + wid;
  if (rloc >= SPLITc) return;
  int grow = s * SPLITc + rloc;
  float inv = invn[N1c + grow];
  const float4* p = (const float4*)(f2 + (size_t)grow * Dc);
  float4 v0 = p[lane];
  float4 v1 = p[lane + 64];
  ushort4 o0, o1;
  o0.x = f2bf(v0.x*inv); o0.y = f2bf(v0.y*inv); o0.z = f2bf(v0.z*inv); o0.w = f2bf(v0.w*inv);
  o1.x = f2bf(v1.x*inv); o1.y = f2bf(v1.y*inv); o1.z = f2bf(v1.z*inv); o1.w = f2bf(v1.w*inv);
  ushort4* q = (ushort4*)(f2nb + (size_t)rloc * Dc);
  q[lane] = o0; q[lane + 64] = o1;
}

// ---------------------------------------------------------------- bf16 MFMA GEMM + classify
// ROUND-3 VERBATIM structure (proven 174 us, MfmaUtil 26%, ~4 blocks/CU):
// 128x128 tile, BK=64, 4 waves (2x2), serial stage with 2 barriers/K-step.
// NEW: T1 XCD column-chunk swizzle. Grid x = 192 col-tiles, x-major dispatch,
// 192 % 8 == 0 -> XCD = bx & 7. Remap col_tile = (bx&7)*24 + (bx>>3): each
// XCD owns 24 contiguous column tiles -> its B working set = 3.07 MB,
// resident in its 4 MB L2 across all 32 row sweeps (B re-reads become L2 hits).
__global__ __launch_bounds__(256, 2) void sim_mfma_k(
    const unsigned short* __restrict__ Abf, const unsigned short* __restrict__ Bbf,
    const int* __restrict__ labels, const int* __restrict__ indexes,
    const int* __restrict__ labels_db, const int* __restrict__ indexes_db,
    u64* __restrict__ msim, u64* __restrict__ mamb,
    unsigned* __restrict__ cands, int* __restrict__ ccount, int s)
{
  __shared__ unsigned short As[128 * 64];   // 16 KB, rows of 128B, slot-swizzled
  __shared__ unsigned short Bs[128 * 64];   // 16 KB
  __shared__ u64 wS[128][2];
  __shared__ u64 wA[128][2];

  const int tid  = threadIdx.x;
  const int lane = tid & 63;
  const int wid  = tid >> 6;
  const int wm   = wid >> 1, wn = wid & 1;
  const int rbase = blockIdx.y * 128;
  // T1 bijective XCD chunk swizzle (192 = 8 * 24)
  const int bx   = blockIdx.x;
  const int cbase = ((bx & 7) * 24 + (bx >> 3)) * 128;   // column within split

  f32x4 acc[4][4];
  #pragma unroll
  for (int i = 0; i < 4; ++i)
    #pragma unroll
    for (int j = 0; j < 4; ++j) acc[i][j] = (f32x4){0.f, 0.f, 0.f, 0.f};

  for (int kb = 0; kb < Dc; kb += 64) {
    __syncthreads();
    #pragma unroll
    for (int c4 = 0; c4 < 4; ++c4) {
      int c   = wid * 4 + c4;                 // chunk 0..15 (8 rows each)
      int row = c * 8 + (lane >> 3);
      int ls  = (lane & 7) ^ (row & 7);       // logical k-slot for this phys slot
      const unsigned short* ga = Abf + (size_t)(rbase + row) * Dc + kb + ls * 8;
      const unsigned short* gb = Bbf + (size_t)(cbase + row) * Dc + kb + ls * 8;
      __builtin_amdgcn_global_load_lds((const __attribute__((address_space(1))) void*)ga,
          (__attribute__((address_space(3))) void*)(As + c * 512), 16, 0, 0);
      __builtin_amdgcn_global_load_lds((const __attribute__((address_space(1))) void*)gb,
          (__attribute__((address_space(3))) void*)(Bs + c * 512), 16, 0, 0);
    }
    __syncthreads();   // compiler drains vmcnt before barrier
    #pragma unroll
    for (int kk = 0; kk < 2; ++kk) {
      bf16x8 a[4], b[4];
      #pragma unroll
      for (int mi = 0; mi < 4; ++mi) {
        int r  = wm * 64 + mi * 16 + (lane & 15);
        int ps = (kk * 4 + (lane >> 4)) ^ (r & 7);
        a[mi] = *(const bf16x8*)(const void*)(As + r * 64 + ps * 8);
      }
      #pragma unroll
      for (int ni = 0; ni < 4; ++ni) {
        int r  = wn * 64 + ni * 16 + (lane & 15);
        int ps = (kk * 4 + (lane >> 4)) ^ (r & 7);
        b[ni] = *(const bf16x8*)(const void*)(Bs + r * 64 + ps * 8);
      }
      #pragma unroll
      for (int mi = 0; mi < 4; ++mi)
        #pragma unroll
        for (int ni = 0; ni < 4; ++ni)
          acc[mi][ni] = __builtin_amdgcn_mfma_f32_16x16x32_bf16(a[mi], b[ni], acc[mi][ni], 0, 0, 0);
    }
  }

  // ---- classify into bit masks (C layout: col=lane&15, row=(lane>>4)*4+reg) ----
  wS[tid >> 1][tid & 1] = 0;
  wA[tid >> 1][tid & 1] = 0;
  __syncthreads();

  int lab2[4], idx2[4], cloc[4];
  #pragma unroll
  for (int ni = 0; ni < 4; ++ni) {
    cloc[ni] = cbase + wn * 64 + ni * 16 + (lane & 15);
    int gc = s * SPLITc + cloc[ni];
    lab2[ni] = labels_db[gc];
    idx2[ni] = indexes_db[gc];
  }

  #pragma unroll
  for (int mi = 0; mi < 4; ++mi) {
    #pragma unroll
    for (int r = 0; r < 4; ++r) {
      int row128 = wm * 64 + mi * 16 + (lane >> 4) * 4 + r;
      int gr = rbase + row128;
      int lab1 = labels[gr], idx1 = indexes[gr];
      u64 sb = 0, ab = 0;
      #pragma unroll
      for (int ni = 0; ni < 4; ++ni) {
        float v = acc[mi][ni][r];
        if (idx1 < idx2[ni] && lab1 != lab2[ni]) {
          if (v > SIM_Tc + DELTAc) {
            sb |= 1ull << (ni * 16 + (lane & 15));
          } else if (v > AMB_Tc - DELTAc) {
            if (v < SIM_Tc - DELTAc && v > AMB_Tc + DELTAc) {
              ab |= 1ull << (ni * 16 + (lane & 15));
            } else {   // within ±DELTA of a threshold: exact f32 recheck later
              int ci = atomicAdd(ccount, 1);
              if (ci < CANDMAX)
                cands[ci] = ((unsigned)gr << 15) | (unsigned)cloc[ni];
            }
          }
        }
      }
      if (sb) atomicOr(&wS[row128][wn], sb);
      if (ab) atomicOr(&wA[row128][wn], ab);
    }
  }
  __syncthreads();
  {
    int row128 = tid >> 1, jh = tid & 1;
    size_t w = (size_t)(rbase + row128) * WPSc + (cbase >> 6) + jh;
    msim[w] = wS[row128][jh];
    mamb[w] = wA[row128][jh];
  }
}

// ---------------------------------------------------------------- exact f32 recheck of band pairs
__global__ void sim_recheck_k(const float* __restrict__ f1, const float* __restrict__ f2,
                              const float* __restrict__ invn,
                              const unsigned* __restrict__ cands, const int* __restrict__ ccount,
                              u64* __restrict__ msim, u64* __restrict__ mamb, int s) {
  int lane = threadIdx.x & 63;
  int gw = (blockIdx.x * blockDim.x + threadIdx.x) >> 6;
  int nw = (gridDim.x * blockDim.x) >> 6;
  int n = *ccount; if (n > CANDMAX) n = CANDMAX;
  for (int i = gw; i < n; i += nw) {
    unsigned pk = cands[i];
    int r = (int)(pk >> 15), c = (int)(pk & 0x7fffu);
    const float4* pa = (const float4*)(f1 + (size_t)r * Dc);
    const float4* pb = (const float4*)(f2 + ((size_t)s * SPLITc + c) * Dc);
    float4 a0 = pa[lane], a1 = pa[lane + 64];
    float4 b0 = pb[lane], b1 = pb[lane + 64];
    float d = a0.x*b0.x + a0.y*b0.y + a0.z*b0.z + a0.w*b0.w
            + a1.x*b1.x + a1.y*b1.y + a1.z*b1.z + a1.w*b1.w;
    #pragma unroll
    for (int t = 1; t < 64; t <<= 1) d += __shfl_xor(d, t);
    if (lane == 0) {
      float v = d * invn[r] * invn[N1c + s * SPLITc + c];
      if (v > SIM_Tc)
        atomicOr(&msim[(size_t)r * WPSc + (c >> 6)], 1ull << (c & 63));
      else if (v > AMB_Tc)
        atomicOr(&mamb[(size_t)r * WPSc + (c >> 6)], 1ull << (c & 63));
    }
  }
}

// ---------------------------------------------------------------- per-row counts
__global__ void sim_rowcount_k(const u64* __restrict__ msim, const u64* __restrict__ mamb,
                               int* __restrict__ rowcnt) {
  int row = blockIdx.x;
  int wid = threadIdx.x >> 6, lane = threadIdx.x & 63;
  const u64* m = wid ? mamb : msim;
  int ssum = 0;
  #pragma unroll
  for (int it = 0; it < WPSc / 64; ++it)
    ssum += __popcll(m[(size_t)row * WPSc + it * 64 + lane]);
  #pragma unroll
  for (int d = 32; d; d >>= 1) ssum += __shfl_down(ssum, d);
  if (lane == 0) rowcnt[wid * N1c + row] = ssum;
}

// ---------------------------------------------------------------- exclusive scan over 4096 rows
__global__ void sim_scan_k(const int* __restrict__ rowcnt, int* __restrict__ rowoff) {
  int cat = blockIdx.x;
  int tid = threadIdx.x;                  // 256 threads x 16 rows
  int v[16]; int ssum = 0;
  #pragma unroll
  for (int i = 0; i < 16; ++i) { v[i] = rowcnt[cat * N1c + tid * 16 + i]; ssum += v[i]; }
  int lane = tid & 63, wid = tid >> 6;
  int incl = ssum;
  #pragma unroll
  for (int d = 1; d < 64; d <<= 1) { int t = __shfl_up(incl, d); if (lane >= d) incl += t; }
  __shared__ int wsum[4];
  if (lane == 63) wsum[wid] = incl;
  __syncthreads();
  int woff = 0;
  for (int w = 0; w < wid; ++w) woff += wsum[w];
  int run = woff + incl - ssum;
  #pragma unroll
  for (int i = 0; i < 16; ++i) { rowoff[cat * N1c + tid * 16 + i] = run; run += v[i]; }
}

// ---------------------------------------------------------------- ordered scatter
__global__ void sim_scatter_k(const u64* __restrict__ msim, const u64* __restrict__ mamb,
                              const int* __restrict__ rowoff,
                              const int* __restrict__ labels, const int* __restrict__ counts,
                              const int* __restrict__ labels_db, const int* __restrict__ counts_db,
                              int* __restrict__ out, int s) {
  int row = blockIdx.x;
  int cat = blockIdx.y;
  int lane = threadIdx.x;
  const u64* m = cat ? mamb : msim;
  int* o = out + (cat ? (NSPLITc * CAPc * 2 + s * CAPc * 2) : (s * CAPc * 2));
  int run = rowoff[cat * N1c + row];
  int lab1 = labels[row];
  int cnt1 = counts[row];
  for (int it = 0; it < WPSc / 64; ++it) {
    int w = it * 64 + lane;
    u64 x = m[(size_t)row * WPSc + w];
    int pc = __popcll(x);
    int incl = pc;
    #pragma unroll
    for (int d = 1; d < 64; d <<= 1) { int t = __shfl_up(incl, d); if (lane >= d) incl += t; }
    int pos = run + incl - pc;
    int tot = __shfl(incl, 63);
    while (x) {
      int b = __builtin_ctzll(x);
      x &= x - 1;
      if (pos < CAPc) {
        int gc = s * SPLITc + w * 64 + b;
        int l2v = labels_db[gc];
        if (cat == 0) {
          o[2 * pos]     = lab1;
          o[2 * pos + 1] = l2v;
        } else {
          bool sw = cnt1 > counts_db[gc];
          o[2 * pos]     = sw ? l2v : lab1;
          o[2 * pos + 1] = sw ? lab1 : l2v;
        }
      }
      ++pos;
    }
    run += tot;
  }
}

// ---------------------------------------------------------------- launcher
extern "C" void kernel_launch(void* const* d_in, const int* in_sizes, int n_in,
                              void* d_out, int out_size, void* d_ws, size_t ws_size,
                              hipStream_t stream) {
  const float* features    = (const float*)d_in[0];
  const int*   labels      = (const int*)  d_in[1];
  const int*   counts      = (const int*)  d_in[2];
  const int*   indexes     = (const int*)  d_in[3];
  const float* features_db = (const float*)d_in[4];
  const int*   labels_db   = (const int*)  d_in[5];
  const int*   counts_db   = (const int*)  d_in[6];
  const int*   indexes_db  = (const int*)  d_in[7];
  int* out = (int*)d_out;

  // workspace layout (~57.5 MB)
  u64*   msim   = (u64*)d_ws;                           // 12.58 MB
  u64*   mamb   = msim + (size_t)N1c * WPSc;            // 12.58 MB
  float* invn   = (float*)(mamb + (size_t)N1c * WPSc);  // (N1+N2) f32
  int*   rowcnt = (int*)(invn + (N1c + N2c));           // [2][N1]
  int*   rowoff = rowcnt + 2 * N1c;                     // [2][N1]
  int*   ccount = rowoff + 2 * N1c;                     // 1 (+pad)
  unsigned* cands = (unsigned*)(ccount + 4);            // 4 MB
  unsigned short* f1nb = (unsigned short*)(cands + CANDMAX);  // 4 MB
  unsigned short* f2nb = f1nb + (size_t)N1c * Dc;       // 24 MB (per split, reused)

  sim_fill_out_k<<<(out_size + 255) / 256, 256, 0, stream>>>(out, out_size);
  sim_norm_k<<<(N1c + N2c + 3) / 4, 256, 0, stream>>>(features, features_db, invn, f1nb, f2nb);

  for (int s = 0; s < NSPLITc; ++s) {
    if (s) sim_conv2_k<<<SPLITc / 4, 256, 0, stream>>>(features_db, invn, f2nb, s);
    sim_zero_k<<<1, 64, 0, stream>>>(ccount);
    sim_mfma_k<<<dim3(SPLITc / 128, N1c / 128), 256, 0, stream>>>(
        f1nb, f2nb, labels, indexes, labels_db, indexes_db,
        msim, mamb, cands, ccount, s);
    sim_recheck_k<<<512, 256, 0, stream>>>(features, features_db, invn,
                                           cands, ccount, msim, mamb, s);
    sim_rowcount_k<<<N1c, 128, 0, stream>>>(msim, mamb, rowcnt);
    sim_scan_k<<<2, 256, 0, stream>>>(rowcnt, rowoff);
    sim_scatter_k<<<dim3(N1c, 2), 64, 0, stream>>>(
        msim, mamb, rowoff, labels, counts, labels_db, counts_db, out, s);
  }
}